// Round 7
// baseline (983.604 us; speedup 1.0000x reference)
//
#include <hip/hip_runtime.h>
#include <hip/hip_bf16.h>

// Problem constants
#define BB 16
#define LL 1024
#define DD 384
#define FF 1536
#define KK 3
#define T_OUT 10240
#define MAX_DUR 10

#define PADL 1026                 // per-batch padded rows: [0]=zero, [1..1024]=data, [1025]=zero
#define LO_SCALE 2048.0f          // 2^11: keeps lo parts out of fp16-denormal range
#define LO_INV   4.8828125e-4f    // 2^-11

typedef _Float16 f16x8 __attribute__((ext_vector_type(8)));
typedef float    f32x4 __attribute__((ext_vector_type(4)));

__device__ __forceinline__ void gll16(const void* g, void* l) {
    __builtin_amdgcn_global_load_lds(
        (const __attribute__((address_space(1))) void*)g,
        (__attribute__((address_space(3))) void*)l, 16, 0, 0);
}

__device__ __forceinline__ void split_write(float v, _Float16* hi, _Float16* lo, size_t off) {
    _Float16 h = (_Float16)v;
    hi[off] = h;
    lo[off] = (_Float16)((v - (float)h) * LO_SCALE);
}

__device__ __forceinline__ float split_read(const _Float16* hi, const _Float16* lo, size_t off) {
    return (float)hi[off] + (float)lo[off] * LO_INV;
}

// ---- weight pack: (O,I,3) -> MFMA-fragment-major hi/lo --------------------
// frag layout: [o_tile][ktl][lane][e8], 8 halfs per lane (16 B).
// ktl ordering matches the GEMM k-loop: kseg = ktl%3 (fastest), d0 = (ktl/3)*32.
__global__ void wfrag_k(const float* __restrict__ w, _Float16* __restrict__ hi,
                        _Float16* __restrict__ lo, int O, int I) {
    int id = blockIdx.x * 256 + threadIdx.x;
    int total = O * 3 * I;
    if (id >= total) return;
    int e = id & 7;
    int lane = (id >> 3) & 63;
    int rest = id >> 9;              // o_tile * nKT + ktl
    int nKT = (3 * I) >> 5;
    int ktl = rest % nKT;
    int ot = rest / nKT;
    int o = ot * 16 + (lane & 15);
    int koff = ((lane >> 4) << 3) + e;
    int kseg = ktl % 3;
    int i = (ktl / 3) * 32 + koff;
    float v = w[(o * I + i) * 3 + kseg];
    split_write(v, hi, lo, id);
}

// ---------------- y split into padded hi/lo layout ---------------------------
__global__ void ysplit_k(const float* __restrict__ y, _Float16* __restrict__ hi,
                         _Float16* __restrict__ lo) {
    int id = blockIdx.x * 256 + threadIdx.x;     // BB*PADL*DD
    if (id >= BB * PADL * DD) return;
    int d = id % DD;
    int r = id / DD;
    int b = r / PADL;
    int lr = r - b * PADL;
    float v = 0.f;
    if (lr >= 1 && lr <= LL) v = y[((size_t)(b << 10) + (lr - 1)) * DD + d];
    split_write(v, hi, lo, id);
}

// ---------------- zero the halo pad rows of a padded split buffer ------------
__global__ void padzero_k(_Float16* __restrict__ hi, _Float16* __restrict__ lo, int width) {
    int id = blockIdx.x * 256 + threadIdx.x;     // BB*2*width
    if (id >= BB * 2 * width) return;
    int b = id / (2 * width);
    int rem = id - b * 2 * width;
    int row = (rem / width) ? (PADL - 1) : 0;
    int c = rem % width;
    size_t off = (size_t)(b * PADL + row) * width + c;
    hi[off] = (_Float16)0.f;
    lo[off] = (_Float16)0.f;
}

// ---------------- split-fp16 MFMA conv-GEMM, B in registers ------------------
// Round-7: R3-R6 showed the k-loop is capped ~50-55% MfmaUtil because B
// through LDS double-pays bandwidth (gll16 write + ds_read, x2 wave dup):
// R4 LDS demand ~188% of the 112 B/cyc/CU peak at MFMA pace. Fix: B never
// touches LDS. Weights are 7 MB (L2/L3-resident), frag-major, so each wave
// loads its 4 B-frags per phase straight to registers (coalesced dwordx4),
// software-pipelined ONE PHASE AHEAD with ping-pong reg sets.
//  * LDS holds only A (conv-reuse, double-buffered, 33.3 KB) -> per-phase
//    LDS demand ~71% of peak, no longer binding; 3 blocks/CU.
//  * ONE barrier per super-tile (A buffer WAR); B needs no barriers.
//  * Counted vmcnt ledger (verified): s0: issue B(p+1)+stageA(j+1), wait
//    vmcnt(10); s1: issue B(p+2), wait vmcnt(10); s2: issue B(p+3), wait
//    vmcnt(4) (drains A(j+1), issued 2 phases earlier, BEFORE the barrier
//    so every wave's A-stage is complete before any wave reads it).
//  * Macro-unroll 2 super-tiles (6 phases) so reg-set parity is static.
template<int CIN, int COUT, int KTOT, int NN>
__global__ __launch_bounds__(256, 3) void gemm_breg(
        const _Float16* __restrict__ Ahi, const _Float16* __restrict__ Alo,
        const _Float16* __restrict__ WfH, const _Float16* __restrict__ WfL,
        const float* __restrict__ bias,
        _Float16* __restrict__ Ohi, _Float16* __restrict__ Olo) {
    constexpr int BM   = 128;
    constexpr int AC   = (BM + 2) * 4;       // A 16B-chunks per comp (520)
    constexpr int AC4  = AC / 4;             // per-wave chunks (130)
    constexpr int AIT  = (AC4 + 63) / 64;    // stage iters (3)
    constexpr int AHH  = AC * 8;             // halfs per comp (4160)
    constexpr int nKT  = KTOT >> 5;
    constexpr int nJ   = nKT / 3;            // super-tiles (even for both gemms)
    __shared__ __align__(16) _Float16 lds_h[4 * AHH];   // A dbuf only (33.3 KB)
    const int tid = threadIdx.x;
    const int lane = tid & 63;
    const int w = tid >> 6;
    const int lm = lane & 15, lq = lane >> 4;
    // XCD-aware remap: group-of-4 m-tiles, n fastest inside the group
    const int xcd = blockIdx.x & 7;
    const int t2 = blockIdx.x >> 3;
    const int g  = t2 / (4 * NN);
    const int r  = t2 - g * (4 * NN);
    const int n_t = r >> 2;
    const int mi  = r & 3;
    const int m_t = ((g * 4 + mi) << 3) + xcd;
    const int m0 = m_t * BM;
    const int n0 = n_t * 64;
    const int b = m0 >> 10;
    const int l0 = m0 & 1023;
    const int rowBase = b * PADL + l0;           // padded source row of tap -1
    const int wm = (w >> 1) * 64, wn = (w & 1) * 32;

    f32x4 accM[4][2], accC[4][2];
    const f32x4 zz = {0.f, 0.f, 0.f, 0.f};
    #pragma unroll
    for (int i = 0; i < 4; ++i)
        #pragma unroll
        for (int jj = 0; jj < 2; ++jj) { accM[i][jj] = zz; accC[i][jj] = zz; }

    // ---- invariant per-lane offsets --------------------------------------
    int aRowK[AIT];
    bool aAct[AIT];
    #pragma unroll
    for (int it = 0; it < AIT; ++it) {
        int cl = it * 64 + lane;
        int s  = w * AC4 + cl;
        int p = s >> 3, sl = s & 7;
        int t = sl ^ (p & 7);
        int m = p * 2 + (t >> 2);
        int k8 = t & 3;
        aRowK[it] = (rowBase + m) * CIN + k8 * 8;
        aAct[it] = (cl < AC4);
    }
    int baseB[2];                           // per-jj global frag base (+ p*512)
    #pragma unroll
    for (int jj = 0; jj < 2; ++jj) {
        int ntg = (n0 >> 4) + (w & 1) * 2 + jj;
        baseB[jj] = (ntg * nKT * 64 + lane) * 8;
    }
    int aOff[12];                           // t = s*4+i, row = wm+i*16+lm+s
    #pragma unroll
    for (int t = 0; t < 12; ++t) {
        int row = wm + (t & 3) * 16 + lm + (t >> 2);
        int p = row >> 1;
        int sl = (((row & 1) << 2) | lq) ^ (p & 7);
        aOff[t] = p * 64 + sl * 8;
    }

    auto stageA = [&](int jt, int bidx) {   // 6 gll16 per wave
        int d0 = jt << 5;
        _Float16* abase = lds_h + bidx * (2 * AHH);
        #pragma unroll
        for (int it = 0; it < AIT; ++it) {
            size_t aoff = (size_t)(unsigned)(aRowK[it] + d0);
            _Float16* hb = abase + (w * AC4 + it * 64) * 8;  // wave-uniform
            if (aAct[it]) {
                gll16(Ahi + aoff, hb);
                gll16(Alo + aoff, hb + AHH);
            }
        }
    };

    auto loadB = [&](int p, f16x8* dH, f16x8* dL) {   // 4 global b128 per wave
        int pc = p < nKT ? p : nKT - 1;
        #pragma unroll
        for (int jj = 0; jj < 2; ++jj) {
            size_t off = (size_t)(unsigned)(baseB[jj] + pc * 512);
            dH[jj] = *(const f16x8*)(WfH + off);
            dL[jj] = *(const f16x8*)(WfL + off);
        }
    };

    auto compute = [&](const _Float16* ab, int s, const f16x8* bh, const f16x8* bl) {
        __builtin_amdgcn_s_setprio(1);
        #pragma unroll
        for (int i = 0; i < 4; ++i) {
            int off = aOff[s * 4 + i];       // s,i literals -> reg-resident
            f16x8 aH = *(const f16x8*)(ab + off);
            f16x8 aL = *(const f16x8*)(ab + AHH + off);
            #pragma unroll
            for (int jj = 0; jj < 2; ++jj) {
                accM[i][jj] = __builtin_amdgcn_mfma_f32_16x16x32_f16(aH, bh[jj], accM[i][jj], 0, 0, 0);
                accC[i][jj] = __builtin_amdgcn_mfma_f32_16x16x32_f16(aH, bl[jj], accC[i][jj], 0, 0, 0);
                accC[i][jj] = __builtin_amdgcn_mfma_f32_16x16x32_f16(aL, bh[jj], accC[i][jj], 0, 0, 0);
            }
        }
        __builtin_amdgcn_s_setprio(0);
    };

    // prologue: A(0)->buf0 [6], B(0)->set0 [4]; drain A(0), keep B(0)
    f16x8 b0H[2], b0L[2], b1H[2], b1L[2];
    stageA(0, 0);
    __builtin_amdgcn_sched_barrier(0);
    loadB(0, b0H, b0L);
    __builtin_amdgcn_sched_barrier(0);
    asm volatile("s_waitcnt vmcnt(4)" ::: "memory");
    __builtin_amdgcn_s_barrier();

    for (int jm = 0; jm < nJ; jm += 2) {
        const _Float16* bufE = lds_h;                   // A(jm)   (even -> buf0)
        const _Float16* bufO = lds_h + 2 * AHH;         // A(jm+1) (odd  -> buf1)
        const int p0 = 3 * jm;
        // ---- super-tile jm: phases s=0,1,2 (sets 0,1,0) -------------------
        loadB(p0 + 1, b1H, b1L);
        stageA(jm + 1 < nJ ? jm + 1 : nJ - 1, 1);
        __builtin_amdgcn_sched_barrier(0);
        asm volatile("s_waitcnt vmcnt(10)" ::: "memory");
        __builtin_amdgcn_sched_barrier(0);
        compute(bufE, 0, b0H, b0L);
        __builtin_amdgcn_sched_barrier(0);

        loadB(p0 + 2, b0H, b0L);
        __builtin_amdgcn_sched_barrier(0);
        asm volatile("s_waitcnt vmcnt(10)" ::: "memory");
        __builtin_amdgcn_sched_barrier(0);
        compute(bufE, 1, b1H, b1L);
        __builtin_amdgcn_sched_barrier(0);

        loadB(p0 + 3, b1H, b1L);
        __builtin_amdgcn_sched_barrier(0);
        asm volatile("s_waitcnt vmcnt(4)" ::: "memory");  // drains A(jm+1) too
        __builtin_amdgcn_sched_barrier(0);
        compute(bufE, 2, b0H, b0L);
        __builtin_amdgcn_sched_barrier(0);
        __builtin_amdgcn_s_barrier();                     // buf0 free for WAR
        // ---- super-tile jm+1: phases s=0,1,2 (sets 1,0,1) -----------------
        loadB(p0 + 4, b0H, b0L);
        stageA(jm + 2 < nJ ? jm + 2 : nJ - 1, 0);
        __builtin_amdgcn_sched_barrier(0);
        asm volatile("s_waitcnt vmcnt(10)" ::: "memory");
        __builtin_amdgcn_sched_barrier(0);
        compute(bufO, 0, b1H, b1L);
        __builtin_amdgcn_sched_barrier(0);

        loadB(p0 + 5, b1H, b1L);
        __builtin_amdgcn_sched_barrier(0);
        asm volatile("s_waitcnt vmcnt(10)" ::: "memory");
        __builtin_amdgcn_sched_barrier(0);
        compute(bufO, 1, b0H, b0L);
        __builtin_amdgcn_sched_barrier(0);

        loadB(p0 + 6, b0H, b0L);
        __builtin_amdgcn_sched_barrier(0);
        asm volatile("s_waitcnt vmcnt(4)" ::: "memory");  // drains A(jm+2) too
        __builtin_amdgcn_sched_barrier(0);
        compute(bufO, 2, b1H, b1L);
        __builtin_amdgcn_sched_barrier(0);
        __builtin_amdgcn_s_barrier();                     // buf1 free for WAR
    }
    // epilogue: bias + relu + re-split to padded hi/lo output
    #pragma unroll
    for (int i = 0; i < 4; ++i)
        #pragma unroll
        for (int jj = 0; jj < 2; ++jj) {
            int n_g = n0 + wn + jj * 16 + lm;
            float bv = bias[n_g];
            #pragma unroll
            for (int rr = 0; rr < 4; ++rr) {
                int l = l0 + wm + i * 16 + lq * 4 + rr;
                float v = accM[i][jj][rr] + accC[i][jj][rr] * LO_INV + bv;
                v = fmaxf(v, 0.f);
                size_t off = (size_t)(b * PADL + 1 + l) * COUT + n_g;
                split_write(v, Ohi, Olo, off);
            }
        }
}

// ---------------- layernorm in place on split buffer (width 384) -------------
__global__ __launch_bounds__(128) void ln_split_k(
        _Float16* __restrict__ hi, _Float16* __restrict__ lo,
        const float* __restrict__ g, const float* __restrict__ be) {
    const int row = blockIdx.x;
    const int b = row >> 10, l = row & 1023;
    const size_t base = (size_t)(b * PADL + 1 + l) * DD;
    const int tid = threadIdx.x;
    float v0 = split_read(hi, lo, base + tid);
    float v1 = split_read(hi, lo, base + tid + 128);
    float v2 = split_read(hi, lo, base + tid + 256);

    __shared__ float sh[2];
    float s = v0 + v1 + v2;
    #pragma unroll
    for (int o = 32; o > 0; o >>= 1) s += __shfl_down(s, o, 64);
    if ((tid & 63) == 0) sh[tid >> 6] = s;
    __syncthreads();
    float mu = (sh[0] + sh[1]) * (1.f / DD);
    __syncthreads();
    float d0 = v0 - mu, d1 = v1 - mu, d2 = v2 - mu;
    float q = d0 * d0 + d1 * d1 + d2 * d2;
    #pragma unroll
    for (int o = 32; o > 0; o >>= 1) q += __shfl_down(q, o, 64);
    if ((tid & 63) == 0) sh[tid >> 6] = q;
    __syncthreads();
    float var = (sh[0] + sh[1]) * (1.f / DD);
    float rs = rsqrtf(var + 1e-5f);
    split_write(d0 * rs * g[tid] + be[tid], hi, lo, base + tid);
    split_write(d1 * rs * g[tid + 128] + be[tid + 128], hi, lo, base + tid + 128);
    split_write(d2 * rs * g[tid + 256] + be[tid + 256], hi, lo, base + tid + 256);
}

// ---------------- layernorm + length predictor on split buffer ---------------
__global__ __launch_bounds__(128) void ln_pred_split_k(
        const _Float16* __restrict__ hi, const _Float16* __restrict__ lo,
        const float* __restrict__ g, const float* __restrict__ be,
        const float* __restrict__ wl, const float* __restrict__ bl,
        const int* __restrict__ token_lengths, int* __restrict__ lns) {
    const int row = blockIdx.x;
    const int b = row >> 10, l = row & 1023;
    const size_t base = (size_t)(b * PADL + 1 + l) * DD;
    const int tid = threadIdx.x;
    float v0 = split_read(hi, lo, base + tid);
    float v1 = split_read(hi, lo, base + tid + 128);
    float v2 = split_read(hi, lo, base + tid + 256);

    __shared__ float sh[2];
    float s = v0 + v1 + v2;
    #pragma unroll
    for (int o = 32; o > 0; o >>= 1) s += __shfl_down(s, o, 64);
    if ((tid & 63) == 0) sh[tid >> 6] = s;
    __syncthreads();
    float mu = (sh[0] + sh[1]) * (1.f / DD);
    __syncthreads();
    float d0 = v0 - mu, d1 = v1 - mu, d2 = v2 - mu;
    float q = d0 * d0 + d1 * d1 + d2 * d2;
    #pragma unroll
    for (int o = 32; o > 0; o >>= 1) q += __shfl_down(q, o, 64);
    if ((tid & 63) == 0) sh[tid >> 6] = q;
    __syncthreads();
    float var = (sh[0] + sh[1]) * (1.f / DD);
    float rs = rsqrtf(var + 1e-5f);
    __syncthreads();
    float p = (d0 * rs * g[tid]       + be[tid])       * wl[tid]
            + (d1 * rs * g[tid + 128] + be[tid + 128]) * wl[tid + 128]
            + (d2 * rs * g[tid + 256] + be[tid + 256]) * wl[tid + 256];
    #pragma unroll
    for (int o = 32; o > 0; o >>= 1) p += __shfl_down(p, o, 64);
    if ((tid & 63) == 0) sh[tid >> 6] = p;
    __syncthreads();
    if (tid == 0) {
        float pred = sh[0] + sh[1] + bl[0];
        float e = expf(pred);           // ALPHA == 1.0
        float r = rintf(e);             // round-half-even, matches jnp.round
        r = fminf(fmaxf(r, 0.f), (float)MAX_DUR);
        int v = (int)r;
        if (l >= token_lengths[b]) v = 0;
        lns[row] = v;
    }
}

// ---------------- per-batch inclusive cumsum (L=1024) ------------------------
__global__ __launch_bounds__(1024) void cumsum_k(
        const int* __restrict__ lns, int* __restrict__ csum,
        float* __restrict__ totals_out) {
    __shared__ int s[1024];
    const int b = blockIdx.x, tid = threadIdx.x;
    s[tid] = lns[(b << 10) + tid];
    __syncthreads();
    #pragma unroll
    for (int o = 1; o < 1024; o <<= 1) {
        int t = (tid >= o) ? s[tid - o] : 0;
        __syncthreads();
        s[tid] += t;
        __syncthreads();
    }
    csum[(b << 10) + tid] = s[tid];
    if (tid == 1023) totals_out[b] = (float)s[1023];
}

// ---------------- gather: out[b,t,:] = valid ? y[b, idx(t), :] : 0 -----------
__global__ __launch_bounds__(256) void gather_k(
        const float* __restrict__ y, const int* __restrict__ csum,
        float* __restrict__ out) {
    int gid = blockIdx.x * 256 + threadIdx.x;   // B*T_OUT*96 float4 chunks
    int c4 = gid % 96;
    int rest = gid / 96;
    int t = rest % T_OUT;
    int b = rest / T_OUT;
    const int* c = csum + (b << 10);
    int total = c[1023];
    float4 r = make_float4(0.f, 0.f, 0.f, 0.f);
    if (t < total) {
        int lo = 0, hi = 1024;
        while (lo < hi) {               // searchsorted side='right'
            int mid = (lo + hi) >> 1;
            if (c[mid] <= t) lo = mid + 1; else hi = mid;
        }
        int idx = min(lo, LL - 1);
        r = *(const float4*)(y + ((size_t)((b << 10) + idx)) * DD + (c4 << 2));
    }
    *(float4*)(out + ((size_t)b * T_OUT + t) * DD + (c4 << 2)) = r;
}

// ---------------- host side --------------------------------------------------
extern "C" void kernel_launch(void* const* d_in, const int* in_sizes, int n_in,
                              void* d_out, int out_size, void* d_ws, size_t ws_size,
                              hipStream_t stream) {
    const float* y   = (const float*)d_in[0];
    const int*   tok = (const int*)d_in[1];
    const float* w1a = (const float*)d_in[2];
    const float* b1a = (const float*)d_in[3];
    const float* w1b = (const float*)d_in[4];
    const float* b1b = (const float*)d_in[5];
    const float* g1  = (const float*)d_in[6];
    const float* be1 = (const float*)d_in[7];
    const float* w2a = (const float*)d_in[8];
    const float* b2a = (const float*)d_in[9];
    const float* w2b = (const float*)d_in[10];
    const float* b2b = (const float*)d_in[11];
    const float* g2  = (const float*)d_in[12];
    const float* be2 = (const float*)d_in[13];
    const float* wl  = (const float*)d_in[14];
    const float* bl  = (const float*)d_in[15];

    float* out = (float*)d_out;

    // workspace layout (halfs)
    const size_t WN   = (size_t)FF * DD * KK;          // 1,769,472 per weight comp
    const size_t SN   = (size_t)BB * PADL * DD;        // 6,303,744
    const size_t H1N  = (size_t)BB * PADL * FF;        // 25,214,976
    _Float16* p = (_Float16*)d_ws;
    _Float16* Wh1a = p;              _Float16* Wl1a = Wh1a + WN;
    _Float16* Wh1b = Wl1a + WN;      _Float16* Wl1b = Wh1b + WN;
    _Float16* Wh2a = Wl1b + WN;      _Float16* Wl2a = Wh2a + WN;
    _Float16* Wh2b = Wl2a + WN;      _Float16* Wl2b = Wh2b + WN;
    _Float16* Shi  = Wl2b + WN;      _Float16* Slo  = Shi + SN;
    _Float16* H1hi = Slo + SN;       _Float16* H1lo = H1hi + H1N;
    int* lns  = (int*)(H1lo + H1N);
    int* csum = lns + BB * LL;

    const int M = BB * LL;                              // 16384

    // 1) weight frag-pack+split, y split, pad-zero for H1
    {
        int n = FF * DD * KK;
        wfrag_k<<<(n + 255) / 256, 256, 0, stream>>>(w1a, Wh1a, Wl1a, FF, DD);
        wfrag_k<<<(n + 255) / 256, 256, 0, stream>>>(w1b, Wh1b, Wl1b, DD, FF);
        wfrag_k<<<(n + 255) / 256, 256, 0, stream>>>(w2a, Wh2a, Wl2a, FF, DD);
        wfrag_k<<<(n + 255) / 256, 256, 0, stream>>>(w2b, Wh2b, Wl2b, DD, FF);
        int ny = BB * PADL * DD;
        ysplit_k<<<(ny + 255) / 256, 256, 0, stream>>>(y, Shi, Slo);
        int np = BB * 2 * FF;
        padzero_k<<<(np + 255) / 256, 256, 0, stream>>>(H1hi, H1lo, FF);
    }
    // 2) four conv-GEMMs (1-D grids, XCD-remapped in-kernel), BM=128/BN=64,
    //    A via LDS, B global->reg pipelined:
    //    D->F: 24n x 128m = 3072 blocks = 4.0 rounds of 768 slots (3/CU)
    //    F->D:  6n x 128m =  768 blocks = 1.0 round  of 768 slots (3/CU)
    gemm_breg<DD, FF, 3 * DD, FF / 64>
        <<<(FF / 64) * (M / 128), 256, 0, stream>>>(Shi, Slo, Wh1a, Wl1a, b1a, H1hi, H1lo);
    gemm_breg<FF, DD, 3 * FF, DD / 64>
        <<<(DD / 64) * (M / 128), 256, 0, stream>>>(H1hi, H1lo, Wh1b, Wl1b, b1b, Shi, Slo);
    ln_split_k<<<M, 128, 0, stream>>>(Shi, Slo, g1, be1);
    gemm_breg<DD, FF, 3 * DD, FF / 64>
        <<<(FF / 64) * (M / 128), 256, 0, stream>>>(Shi, Slo, Wh2a, Wl2a, b2a, H1hi, H1lo);
    gemm_breg<FF, DD, 3 * FF, DD / 64>
        <<<(DD / 64) * (M / 128), 256, 0, stream>>>(H1hi, H1lo, Wh2b, Wl2b, b2b, Shi, Slo);
    // 3) predictor + cumsum + gather
    ln_pred_split_k<<<M, 128, 0, stream>>>(Shi, Slo, g2, be2, wl, bl, tok, lns);
    cumsum_k<<<BB, 1024, 0, stream>>>(lns, csum, out + (size_t)BB * T_OUT * DD);
    {
        long long n = (long long)BB * T_OUT * 96;
        gather_k<<<(int)((n + 255) / 256), 256, 0, stream>>>(y, csum, out);
    }
}